// Round 1
// baseline (230.554 us; speedup 1.0000x reference)
//
#include <hip/hip_runtime.h>
#include <hip/hip_bf16.h>

// SS3D selective-scan block, MI355X (gfx950)
// B=2, D_INNER=96, D_MODEL=96, D_STATE=16, DT_RANK=6, L=12^3=1728, 8L=13824
//
// Pipeline:
//  S1: xz = x @ in_proj_w.T  -> xxT[b][c][l] (conv layout), z[b][l][c]
//  S2: depthwise conv3d 3x3x3 SAME + bias + silu -> xconv[b][c][l]
//  S3: build 8 direction permutations -> xs[b][d][p], p in [0,13824)
//  S4: x_dbl = x_proj_w @ xs; delta = softplus(dt_w @ x_dbl[:6] + dt_b);
//      Bst[b][p][n], Cst[b][p][n]  (n-contiguous for scan loads)
//  S5: chunked linear-recurrence scan h = dA*h + dBu over p (chunks of 128)
//      A: per-chunk (prod dA, local end H);  A2: 108-step chunk prefix;
//      B: replay with correct init, y[p] = sum_n h*C + x*Ds -> yT[b][p][d]
//  S6: mean over 8 dirs, LayerNorm(channel), *silu(z), @ out_proj_w.T -> out

#define LSP 1728
#define P8  13824
#define CS  128
#define NC  108

__device__ __forceinline__ float sigmoidf_(float v) { return 1.f / (1.f + __expf(-v)); }

// ---------- S1: input projection ----------
__global__ void s1_inproj(const float* __restrict__ x, const float* __restrict__ w,
                          float* __restrict__ xxT, float* __restrict__ z) {
  __shared__ float xr[96];
  int bl = blockIdx.x;            // b*1728 + l
  int b = bl / LSP, l = bl % LSP;
  int tid = threadIdx.x;          // 0..191 -> output channel c'
  if (tid < 96) xr[tid] = x[bl * 96 + tid];
  __syncthreads();
  float acc = 0.f;
  const float* wr = w + tid * 96;
#pragma unroll 8
  for (int c = 0; c < 96; c++) acc = fmaf(xr[c], wr[c], acc);
  if (tid < 96) xxT[(b * 96 + tid) * LSP + l] = acc;
  else          z[(b * LSP + l) * 96 + (tid - 96)] = acc;
}

// ---------- S2: depthwise conv3d + silu ----------
__global__ void s2_conv(const float* __restrict__ xxT, const float* __restrict__ cw,
                        const float* __restrict__ cb, float* __restrict__ xconv) {
  __shared__ float w[27];
  int bx = blockIdx.x;                 // b*(96*9) + c*9 + lb
  int b = bx / (96 * 9);
  int rem = bx % (96 * 9);
  int c = rem / 9, lb = rem % 9;
  int tid = threadIdx.x;               // 0..191
  if (tid < 27) w[tid] = cw[c * 27 + tid];
  __syncthreads();
  int l = lb * 192 + tid;
  int a = l / 144, r2 = l % 144, bb = r2 / 12, cc = r2 % 12;
  const float* xp = xxT + (b * 96 + c) * LSP;
  float acc = cb[c];
#pragma unroll
  for (int kd = -1; kd <= 1; kd++) {
    int ia = a + kd; if (ia < 0 || ia >= 12) continue;
#pragma unroll
    for (int kw = -1; kw <= 1; kw++) {
      int ib = bb + kw; if (ib < 0 || ib >= 12) continue;
#pragma unroll
      for (int kh = -1; kh <= 1; kh++) {
        int ic = cc + kh; if (ic < 0 || ic >= 12) continue;
        acc = fmaf(xp[ia * 144 + ib * 12 + ic], w[(kd + 1) * 9 + (kw + 1) * 3 + (kh + 1)], acc);
      }
    }
  }
  xconv[(b * 96 + c) * LSP + l] = acc * sigmoidf_(acc);
}

// ---------- S3: direction gather ----------
__global__ void s3_dirs(const float* __restrict__ xconv, float* __restrict__ xs) {
  int t = blockIdx.x * 256 + threadIdx.x;     // < 2*96*13824
  int bd = t / P8, p = t % P8;
  int k = p / LSP, l = p % LSP;
  int lp = (k & 1) ? (LSP - 1 - l) : l;
  int a = lp / 144, r = lp % 144, bb = r / 12, cc = r % 12;
  int s;
  switch (k >> 1) {
    case 0:  s = a * 144 + cc * 12 + bb; break;   // swap(W,H)
    case 1:  s = cc * 144 + bb * 12 + a; break;   // swap(D,H)
    case 2:  s = bb * 144 + a * 12 + cc; break;   // swap(D,W)
    default: s = lp; break;                        // identity
  }
  xs[t] = xconv[bd * LSP + s];
}

// ---------- S4: x_proj + dt projection + softplus ----------
__global__ void s4_proj(const float* __restrict__ xs, const float* __restrict__ xpw,
                        const float* __restrict__ dtw, const float* __restrict__ dtb,
                        float* __restrict__ delta, float* __restrict__ Bst,
                        float* __restrict__ Cst) {
  __shared__ float w[38 * 96];
  __shared__ float dw[96 * 6];
  __shared__ float db[96];
  int tid = threadIdx.x;
  for (int i = tid; i < 38 * 96; i += 256) w[i] = xpw[i];
  for (int i = tid; i < 96 * 6; i += 256) dw[i] = dtw[i];
  if (tid < 96) db[tid] = dtb[tid];
  __syncthreads();
  int pi = blockIdx.x * 256 + tid;   // b*13824 + p
  int b = pi / P8, p = pi % P8;
  float acc[38];
#pragma unroll
  for (int c = 0; c < 38; c++) acc[c] = 0.f;
  const float* xp = xs + b * 96 * P8 + p;
  for (int d = 0; d < 96; d++) {
    float xv = xp[d * P8];
#pragma unroll
    for (int c = 0; c < 38; c++) acc[c] = fmaf(w[c * 96 + d], xv, acc[c]);
  }
  for (int d = 0; d < 96; d++) {
    float s = db[d];
#pragma unroll
    for (int r = 0; r < 6; r++) s = fmaf(dw[d * 6 + r], acc[r], s);
    float sp = fmaxf(s, 0.f) + log1pf(__expf(-fabsf(s)));
    delta[(b * 96 + d) * P8 + p] = sp;
  }
  float4* Bp = (float4*)(Bst + (size_t)pi * 16);
  Bp[0] = make_float4(acc[6], acc[7], acc[8], acc[9]);
  Bp[1] = make_float4(acc[10], acc[11], acc[12], acc[13]);
  Bp[2] = make_float4(acc[14], acc[15], acc[16], acc[17]);
  Bp[3] = make_float4(acc[18], acc[19], acc[20], acc[21]);
  float4* Cp = (float4*)(Cst + (size_t)pi * 16);
  Cp[0] = make_float4(acc[22], acc[23], acc[24], acc[25]);
  Cp[1] = make_float4(acc[26], acc[27], acc[28], acc[29]);
  Cp[2] = make_float4(acc[30], acc[31], acc[32], acc[33]);
  Cp[3] = make_float4(acc[34], acc[35], acc[36], acc[37]);
}

// ---------- S5A: per-chunk scan (prodA, local H) ----------
__global__ void s5a_chunk(const float* __restrict__ delta, const float* __restrict__ xs,
                          const float* __restrict__ Bst, const float* __restrict__ A_logs,
                          float* __restrict__ P, float* __restrict__ H) {
  int bx = blockIdx.x;                  // b*(NC*6) + c*6 + dblk
  int b = bx / (NC * 6);
  int rem = bx % (NC * 6);
  int c = rem / 6, dblk = rem % 6;
  int dl = threadIdx.x >> 4, n = threadIdx.x & 15;
  int d = dblk * 16 + dl;
  float Aval = -__expf(A_logs[d * 16 + n]);
  const float* dp = delta + (b * 96 + d) * P8;
  const float* xp = xs + (b * 96 + d) * P8;
  const float* bp = Bst + (size_t)b * P8 * 16 + n;
  float Pv = 1.f, Hv = 0.f;
  int p0 = c * CS;
#pragma unroll 4
  for (int i = 0; i < CS; i++) {
    int p = p0 + i;
    float dv = dp[p], xv = xp[p], bv = bp[(size_t)p * 16];
    float dA = __expf(dv * Aval);
    Pv *= dA;
    Hv = fmaf(dA, Hv, dv * bv * xv);
  }
  int idx = ((b * 96 + d) * NC + c) * 16 + n;
  P[idx] = Pv;
  H[idx] = Hv;
}

// ---------- S5A2: chunk prefix (sequential over NC) ----------
__global__ void s5a2_prefix(const float* __restrict__ P, const float* __restrict__ H,
                            float* __restrict__ Hinit) {
  int t = blockIdx.x * 256 + threadIdx.x;   // < 2*96*16 = 3072
  int bd = t >> 4, n = t & 15;
  const float* Pp = P + bd * NC * 16 + n;
  const float* Hp = H + bd * NC * 16 + n;
  float* Ip = Hinit + bd * NC * 16 + n;
  float carry = 0.f;
#pragma unroll 4
  for (int c = 0; c < NC; c++) {
    float pv = Pp[c * 16];
    float hv = Hp[c * 16];
    Ip[c * 16] = carry;
    carry = fmaf(pv, carry, hv);
  }
}

// ---------- S5B: replay with init, emit y ----------
__global__ void s5b_scan(const float* __restrict__ delta, const float* __restrict__ xs,
                         const float* __restrict__ Bst, const float* __restrict__ Cst,
                         const float* __restrict__ Hinit, const float* __restrict__ A_logs,
                         const float* __restrict__ Ds, float* __restrict__ yT) {
  int bx = blockIdx.x;
  int b = bx / (NC * 6);
  int rem = bx % (NC * 6);
  int c = rem / 6, dblk = rem % 6;
  int dl = threadIdx.x >> 4, n = threadIdx.x & 15;
  int d = dblk * 16 + dl;
  float Aval = -__expf(A_logs[d * 16 + n]);
  const float* dp = delta + (b * 96 + d) * P8;
  const float* xp = xs + (b * 96 + d) * P8;
  const float* bp = Bst + (size_t)b * P8 * 16 + n;
  const float* cp = Cst + (size_t)b * P8 * 16 + n;
  float dsv = Ds[d];
  int idx = ((b * 96 + d) * NC + c) * 16 + n;
  float h = Hinit[idx];
  int p0 = c * CS;
  for (int i = 0; i < CS; i++) {
    int p = p0 + i;
    float dv = dp[p], xv = xp[p], bv = bp[(size_t)p * 16];
    float dA = __expf(dv * Aval);
    h = fmaf(dA, h, dv * bv * xv);
    float val = h * cp[(size_t)p * 16];
    val += __shfl_xor(val, 1, 16);
    val += __shfl_xor(val, 2, 16);
    val += __shfl_xor(val, 4, 16);
    val += __shfl_xor(val, 8, 16);
    if (n == 0) yT[(size_t)(b * P8 + p) * 96 + d] = fmaf(xv, dsv, val);
  }
}

// ---------- S6: dir-mean + LayerNorm + gate + out_proj ----------
__global__ void s6_out(const float* __restrict__ yT, const float* __restrict__ z,
                       const float* __restrict__ lnw, const float* __restrict__ lnb,
                       const float* __restrict__ wout, float* __restrict__ out) {
  __shared__ float wl[96 * 97];   // padded stride 97 -> conflict-free
  __shared__ float g[96];
  __shared__ float r1[128], r2[128];
  int tid = threadIdx.x;          // 128
  for (int i = tid; i < 96 * 96; i += 128) {
    int cc = i / 96, dd = i % 96;
    wl[cc * 97 + dd] = wout[i];
  }
  int bx = blockIdx.x;            // b*216 + lb  (8 l's per block)
  int b = bx / 216, lb = bx % 216;
  __syncthreads();
  for (int j = 0; j < 8; j++) {
    int l = lb * 8 + j;
    float ym = 0.f, zv = 0.f;
    if (tid < 96) {
      const float* yp = yT + (size_t)(b * P8 + l) * 96 + tid;
#pragma unroll
      for (int k = 0; k < 8; k++) ym += yp[(size_t)k * LSP * 96];
      ym *= 0.125f;
      zv = z[(b * LSP + l) * 96 + tid];
    }
    r1[tid] = (tid < 96) ? ym : 0.f;
    r2[tid] = (tid < 96) ? ym * ym : 0.f;
    __syncthreads();
    for (int s = 64; s > 0; s >>= 1) {
      if (tid < s) { r1[tid] += r1[tid + s]; r2[tid] += r2[tid + s]; }
      __syncthreads();
    }
    float mu = r1[0] * (1.f / 96.f);
    float var = r2[0] * (1.f / 96.f) - mu * mu;
    float rstd = rsqrtf(var + 1e-5f);
    if (tid < 96) {
      float yn = (ym - mu) * rstd * lnw[tid] + lnb[tid];
      g[tid] = yn * (zv * sigmoidf_(zv));
    }
    __syncthreads();
    if (tid < 96) {
      float acc = 0.f;
#pragma unroll 8
      for (int dd = 0; dd < 96; dd++) acc = fmaf(g[dd], wl[tid * 97 + dd], acc);
      out[(b * LSP + l) * 96 + tid] = acc;
    }
    __syncthreads();
  }
}

extern "C" void kernel_launch(void* const* d_in, const int* in_sizes, int n_in,
                              void* d_out, int out_size, void* d_ws, size_t ws_size,
                              hipStream_t stream) {
  const float* x          = (const float*)d_in[0];
  const float* in_proj_w  = (const float*)d_in[1];
  const float* conv_w     = (const float*)d_in[2];
  const float* conv_b     = (const float*)d_in[3];
  const float* x_proj_w   = (const float*)d_in[4];
  const float* dt_w       = (const float*)d_in[5];
  const float* dt_b       = (const float*)d_in[6];
  const float* A_logs     = (const float*)d_in[7];
  const float* Ds         = (const float*)d_in[8];
  const float* ln_w       = (const float*)d_in[9];
  const float* ln_b       = (const float*)d_in[10];
  const float* out_proj_w = (const float*)d_in[11];
  float* out = (float*)d_out;

  float* ws    = (float*)d_ws;
  float* z     = ws;                 // 331776
  float* xxT   = z + 331776;         // 331776
  float* xconv = xxT + 331776;       // 331776
  float* xs    = xconv + 331776;     // 2654208
  float* delta = xs + 2654208;       // 2654208
  float* Bst   = delta + 2654208;    // 442368
  float* Cst   = Bst + 442368;       // 442368
  float* Pbuf  = Cst + 442368;       // 331776
  float* Hbuf  = Pbuf + 331776;      // 331776
  float* Hinit = Hbuf + 331776;      // 331776
  float* yT    = Hinit + 331776;     // 2654208   (total ~43.4 MB)

  s1_inproj<<<2 * LSP, 192, 0, stream>>>(x, in_proj_w, xxT, z);
  s2_conv<<<2 * 96 * 9, 192, 0, stream>>>(xxT, conv_w, conv_b, xconv);
  s3_dirs<<<2 * 96 * P8 / 256, 256, 0, stream>>>(xconv, xs);
  s4_proj<<<2 * P8 / 256, 256, 0, stream>>>(xs, x_proj_w, dt_w, dt_b, delta, Bst, Cst);
  s5a_chunk<<<2 * NC * 6, 256, 0, stream>>>(delta, xs, Bst, A_logs, Pbuf, Hbuf);
  s5a2_prefix<<<12, 256, 0, stream>>>(Pbuf, Hbuf, Hinit);
  s5b_scan<<<2 * NC * 6, 256, 0, stream>>>(delta, xs, Bst, Cst, Hinit, A_logs, Ds, yT);
  s6_out<<<2 * 216, 128, 0, stream>>>(yT, z, ln_w, ln_b, out_proj_w, out);
}

// Round 2
// 182.188 us; speedup vs baseline: 1.2655x; 1.2655x over previous
//
#include <hip/hip_runtime.h>
#include <hip/hip_bf16.h>

// SS3D selective-scan block, MI355X (gfx950)
// B=2, D_INNER=96, D_MODEL=96, D_STATE=16, DT_RANK=6, L=12^3=1728, 8L=13824
//
// Pipeline:
//  S1: xz = x @ in_proj_w.T  -> xxT[b][c][l] (conv layout), z[b][l][c]
//  S2: depthwise conv3d 3x3x3 SAME + bias + silu -> xconv[b][c][l]
//  S3: build 8 direction permutations -> xs[b][d][p], p in [0,13824)
//  S4: x_dbl = x_proj_w @ xs; delta = softplus(dt_w @ x_dbl[:6] + dt_b);
//      Bst[b][p][n], Cst[b][p][n]  (n-contiguous for scan loads)
//      -> LDS-tiled: 64 p per block, 4 waves split 38 channels / 96 delta-d
//  S5: chunked linear-recurrence scan h = dA*h + dBu over p (chunks of 128)
//  S6: mean over 8 dirs, LayerNorm(channel), *silu(z), @ out_proj_w.T -> out

#define LSP 1728
#define P8  13824
#define CS  128
#define NC  108

__device__ __forceinline__ float sigmoidf_(float v) { return 1.f / (1.f + __expf(-v)); }

// ---------- S1: input projection ----------
__global__ void s1_inproj(const float* __restrict__ x, const float* __restrict__ w,
                          float* __restrict__ xxT, float* __restrict__ z) {
  __shared__ float xr[96];
  int bl = blockIdx.x;            // b*1728 + l
  int b = bl / LSP, l = bl % LSP;
  int tid = threadIdx.x;          // 0..191 -> output channel c'
  if (tid < 96) xr[tid] = x[bl * 96 + tid];
  __syncthreads();
  float acc = 0.f;
  const float* wr = w + tid * 96;
#pragma unroll 8
  for (int c = 0; c < 96; c++) acc = fmaf(xr[c], wr[c], acc);
  if (tid < 96) xxT[(b * 96 + tid) * LSP + l] = acc;
  else          z[(b * LSP + l) * 96 + (tid - 96)] = acc;
}

// ---------- S2: depthwise conv3d + silu ----------
__global__ void s2_conv(const float* __restrict__ xxT, const float* __restrict__ cw,
                        const float* __restrict__ cb, float* __restrict__ xconv) {
  __shared__ float w[27];
  int bx = blockIdx.x;                 // b*(96*9) + c*9 + lb
  int b = bx / (96 * 9);
  int rem = bx % (96 * 9);
  int c = rem / 9, lb = rem % 9;
  int tid = threadIdx.x;               // 0..191
  if (tid < 27) w[tid] = cw[c * 27 + tid];
  __syncthreads();
  int l = lb * 192 + tid;
  int a = l / 144, r2 = l % 144, bb = r2 / 12, cc = r2 % 12;
  const float* xp = xxT + (b * 96 + c) * LSP;
  float acc = cb[c];
#pragma unroll
  for (int kd = -1; kd <= 1; kd++) {
    int ia = a + kd; if (ia < 0 || ia >= 12) continue;
#pragma unroll
    for (int kw = -1; kw <= 1; kw++) {
      int ib = bb + kw; if (ib < 0 || ib >= 12) continue;
#pragma unroll
      for (int kh = -1; kh <= 1; kh++) {
        int ic = cc + kh; if (ic < 0 || ic >= 12) continue;
        acc = fmaf(xp[ia * 144 + ib * 12 + ic], w[(kd + 1) * 9 + (kw + 1) * 3 + (kh + 1)], acc);
      }
    }
  }
  xconv[(b * 96 + c) * LSP + l] = acc * sigmoidf_(acc);
}

// ---------- S3: direction gather ----------
__global__ void s3_dirs(const float* __restrict__ xconv, float* __restrict__ xs) {
  int t = blockIdx.x * 256 + threadIdx.x;     // < 2*96*13824
  int bd = t / P8, p = t % P8;
  int k = p / LSP, l = p % LSP;
  int lp = (k & 1) ? (LSP - 1 - l) : l;
  int a = lp / 144, r = lp % 144, bb = r / 12, cc = r % 12;
  int s;
  switch (k >> 1) {
    case 0:  s = a * 144 + cc * 12 + bb; break;   // swap(W,H)
    case 1:  s = cc * 144 + bb * 12 + a; break;   // swap(D,H)
    case 2:  s = bb * 144 + a * 12 + cc; break;   // swap(D,W)
    default: s = lp; break;                        // identity
  }
  xs[t] = xconv[bd * LSP + s];
}

// ---------- S4: x_proj + dt projection + softplus (LDS-tiled) ----------
// grid = 2*P8/64 = 432 blocks, 256 threads (4 waves)
// wave cg handles channels [cg*10, cg*10+10) of the padded 40-channel W,
// then delta rows [cg*24, cg*24+24).
__global__ void s4_proj(const float* __restrict__ xs, const float* __restrict__ xpw,
                        const float* __restrict__ dtw, const float* __restrict__ dtb,
                        float* __restrict__ delta, float* __restrict__ Bst,
                        float* __restrict__ Cst) {
  __shared__ float xt[96][64];     // 24 KB   xs tile
  __shared__ float w[40 * 96];     // 15 KB   x_proj_w padded to 40 rows
  __shared__ float dwv[96 * 6];
  __shared__ float dbv[96];
  __shared__ float accS[6][64];    // dt-rank sums broadcast
  int tid = threadIdx.x;
  int blk = blockIdx.x;
  int b = blk / (P8 / 64);
  int p0 = (blk % (P8 / 64)) * 64;
  for (int i = tid; i < 40 * 96; i += 256) w[i] = (i < 38 * 96) ? xpw[i] : 0.f;
  for (int i = tid; i < 96 * 6; i += 256) dwv[i] = dtw[i];
  if (tid < 96) dbv[tid] = dtb[tid];
  int pl = tid & 63, cg = tid >> 6;   // lane-in-wave = p, wave = channel group
  const float* xsb = xs + (size_t)b * 96 * P8 + p0 + pl;
#pragma unroll
  for (int d0 = 0; d0 < 96; d0 += 4)
    xt[d0 + cg][pl] = xsb[(size_t)(d0 + cg) * P8];
  __syncthreads();

  int c0 = cg * 10;
  float acc[10];
#pragma unroll
  for (int j = 0; j < 10; j++) acc[j] = 0.f;
  for (int d = 0; d < 96; d++) {
    float xv = xt[d][pl];
#pragma unroll
    for (int j = 0; j < 10; j++) acc[j] = fmaf(w[(c0 + j) * 96 + d], xv, acc[j]);
  }
  if (cg == 0) {
#pragma unroll
    for (int j = 0; j < 6; j++) accS[j][pl] = acc[j];
  }
  // B/C stores: each lane's 16 floats for one p are one 64B line
  size_t pi = (size_t)b * P8 + p0 + pl;
#pragma unroll
  for (int j = 0; j < 10; j++) {
    int c = c0 + j;
    if (c >= 6 && c < 22)       Bst[pi * 16 + (c - 6)]  = acc[j];
    else if (c >= 22 && c < 38) Cst[pi * 16 + (c - 22)] = acc[j];
  }
  __syncthreads();
  float a0 = accS[0][pl], a1 = accS[1][pl], a2 = accS[2][pl];
  float a3 = accS[3][pl], a4 = accS[4][pl], a5 = accS[5][pl];
  float* dout = delta + (size_t)b * 96 * P8 + p0 + pl;
#pragma unroll 4
  for (int dd = 0; dd < 24; dd++) {
    int d = cg * 24 + dd;
    const float* dwr = dwv + d * 6;
    float s = dbv[d];
    s = fmaf(dwr[0], a0, s); s = fmaf(dwr[1], a1, s); s = fmaf(dwr[2], a2, s);
    s = fmaf(dwr[3], a3, s); s = fmaf(dwr[4], a4, s); s = fmaf(dwr[5], a5, s);
    float sp = (s > 20.f) ? s : __logf(1.f + __expf(s));
    dout[(size_t)d * P8] = sp;
  }
}

// ---------- S5A: per-chunk scan (prodA, local H) ----------
__global__ void s5a_chunk(const float* __restrict__ delta, const float* __restrict__ xs,
                          const float* __restrict__ Bst, const float* __restrict__ A_logs,
                          float* __restrict__ P, float* __restrict__ H) {
  int bx = blockIdx.x;                  // b*(NC*6) + c*6 + dblk
  int b = bx / (NC * 6);
  int rem = bx % (NC * 6);
  int c = rem / 6, dblk = rem % 6;
  int dl = threadIdx.x >> 4, n = threadIdx.x & 15;
  int d = dblk * 16 + dl;
  float Aval = -__expf(A_logs[d * 16 + n]);
  const float* dp = delta + (b * 96 + d) * P8;
  const float* xp = xs + (b * 96 + d) * P8;
  const float* bp = Bst + (size_t)b * P8 * 16 + n;
  float Pv = 1.f, Hv = 0.f;
  int p0 = c * CS;
#pragma unroll 4
  for (int i = 0; i < CS; i++) {
    int p = p0 + i;
    float dv = dp[p], xv = xp[p], bv = bp[(size_t)p * 16];
    float dA = __expf(dv * Aval);
    Pv *= dA;
    Hv = fmaf(dA, Hv, dv * bv * xv);
  }
  int idx = ((b * 96 + d) * NC + c) * 16 + n;
  P[idx] = Pv;
  H[idx] = Hv;
}

// ---------- S5A2: chunk prefix (sequential over NC) ----------
__global__ void s5a2_prefix(const float* __restrict__ P, const float* __restrict__ H,
                            float* __restrict__ Hinit) {
  int t = blockIdx.x * 256 + threadIdx.x;   // < 2*96*16 = 3072
  int bd = t >> 4, n = t & 15;
  const float* Pp = P + bd * NC * 16 + n;
  const float* Hp = H + bd * NC * 16 + n;
  float* Ip = Hinit + bd * NC * 16 + n;
  float carry = 0.f;
#pragma unroll 4
  for (int c = 0; c < NC; c++) {
    float pv = Pp[c * 16];
    float hv = Hp[c * 16];
    Ip[c * 16] = carry;
    carry = fmaf(pv, carry, hv);
  }
}

// ---------- S5B: replay with init, emit y ----------
__global__ void s5b_scan(const float* __restrict__ delta, const float* __restrict__ xs,
                         const float* __restrict__ Bst, const float* __restrict__ Cst,
                         const float* __restrict__ Hinit, const float* __restrict__ A_logs,
                         const float* __restrict__ Ds, float* __restrict__ yT) {
  int bx = blockIdx.x;
  int b = bx / (NC * 6);
  int rem = bx % (NC * 6);
  int c = rem / 6, dblk = rem % 6;
  int dl = threadIdx.x >> 4, n = threadIdx.x & 15;
  int d = dblk * 16 + dl;
  float Aval = -__expf(A_logs[d * 16 + n]);
  const float* dp = delta + (b * 96 + d) * P8;
  const float* xp = xs + (b * 96 + d) * P8;
  const float* bp = Bst + (size_t)b * P8 * 16 + n;
  const float* cp = Cst + (size_t)b * P8 * 16 + n;
  float dsv = Ds[d];
  int idx = ((b * 96 + d) * NC + c) * 16 + n;
  float h = Hinit[idx];
  int p0 = c * CS;
  for (int i = 0; i < CS; i++) {
    int p = p0 + i;
    float dv = dp[p], xv = xp[p], bv = bp[(size_t)p * 16];
    float dA = __expf(dv * Aval);
    h = fmaf(dA, h, dv * bv * xv);
    float val = h * cp[(size_t)p * 16];
    val += __shfl_xor(val, 1, 16);
    val += __shfl_xor(val, 2, 16);
    val += __shfl_xor(val, 4, 16);
    val += __shfl_xor(val, 8, 16);
    if (n == 0) yT[(size_t)(b * P8 + p) * 96 + d] = fmaf(xv, dsv, val);
  }
}

// ---------- S6: dir-mean + LayerNorm + gate + out_proj ----------
__global__ void s6_out(const float* __restrict__ yT, const float* __restrict__ z,
                       const float* __restrict__ lnw, const float* __restrict__ lnb,
                       const float* __restrict__ wout, float* __restrict__ out) {
  __shared__ float wl[96 * 97];   // padded stride 97 -> conflict-free
  __shared__ float g[96];
  __shared__ float r1[128], r2[128];
  int tid = threadIdx.x;          // 128
  for (int i = tid; i < 96 * 96; i += 128) {
    int cc = i / 96, dd = i % 96;
    wl[cc * 97 + dd] = wout[i];
  }
  int bx = blockIdx.x;            // b*216 + lb  (8 l's per block)
  int b = bx / 216, lb = bx % 216;
  __syncthreads();
  for (int j = 0; j < 8; j++) {
    int l = lb * 8 + j;
    float ym = 0.f, zv = 0.f;
    if (tid < 96) {
      const float* yp = yT + (size_t)(b * P8 + l) * 96 + tid;
#pragma unroll
      for (int k = 0; k < 8; k++) ym += yp[(size_t)k * LSP * 96];
      ym *= 0.125f;
      zv = z[(b * LSP + l) * 96 + tid];
    }
    r1[tid] = (tid < 96) ? ym : 0.f;
    r2[tid] = (tid < 96) ? ym * ym : 0.f;
    __syncthreads();
    for (int s = 64; s > 0; s >>= 1) {
      if (tid < s) { r1[tid] += r1[tid + s]; r2[tid] += r2[tid + s]; }
      __syncthreads();
    }
    float mu = r1[0] * (1.f / 96.f);
    float var = r2[0] * (1.f / 96.f) - mu * mu;
    float rstd = rsqrtf(var + 1e-5f);
    if (tid < 96) {
      float yn = (ym - mu) * rstd * lnw[tid] + lnb[tid];
      g[tid] = yn * (zv * sigmoidf_(zv));
    }
    __syncthreads();
    if (tid < 96) {
      float acc = 0.f;
#pragma unroll 8
      for (int dd = 0; dd < 96; dd++) acc = fmaf(g[dd], wl[tid * 97 + dd], acc);
      out[(b * LSP + l) * 96 + tid] = acc;
    }
    __syncthreads();
  }
}

extern "C" void kernel_launch(void* const* d_in, const int* in_sizes, int n_in,
                              void* d_out, int out_size, void* d_ws, size_t ws_size,
                              hipStream_t stream) {
  const float* x          = (const float*)d_in[0];
  const float* in_proj_w  = (const float*)d_in[1];
  const float* conv_w     = (const float*)d_in[2];
  const float* conv_b     = (const float*)d_in[3];
  const float* x_proj_w   = (const float*)d_in[4];
  const float* dt_w       = (const float*)d_in[5];
  const float* dt_b       = (const float*)d_in[6];
  const float* A_logs     = (const float*)d_in[7];
  const float* Ds         = (const float*)d_in[8];
  const float* ln_w       = (const float*)d_in[9];
  const float* ln_b       = (const float*)d_in[10];
  const float* out_proj_w = (const float*)d_in[11];
  float* out = (float*)d_out;

  float* ws    = (float*)d_ws;
  float* z     = ws;                 // 331776
  float* xxT   = z + 331776;         // 331776
  float* xconv = xxT + 331776;       // 331776
  float* xs    = xconv + 331776;     // 2654208
  float* delta = xs + 2654208;       // 2654208
  float* Bst   = delta + 2654208;    // 442368
  float* Cst   = Bst + 442368;       // 442368
  float* Pbuf  = Cst + 442368;       // 331776
  float* Hbuf  = Pbuf + 331776;      // 331776
  float* Hinit = Hbuf + 331776;      // 331776
  float* yT    = Hinit + 331776;     // 2654208   (total ~43.4 MB)

  s1_inproj<<<2 * LSP, 192, 0, stream>>>(x, in_proj_w, xxT, z);
  s2_conv<<<2 * 96 * 9, 192, 0, stream>>>(xxT, conv_w, conv_b, xconv);
  s3_dirs<<<2 * 96 * P8 / 256, 256, 0, stream>>>(xconv, xs);
  s4_proj<<<2 * P8 / 64, 256, 0, stream>>>(xs, x_proj_w, dt_w, dt_b, delta, Bst, Cst);
  s5a_chunk<<<2 * NC * 6, 256, 0, stream>>>(delta, xs, Bst, A_logs, Pbuf, Hbuf);
  s5a2_prefix<<<12, 256, 0, stream>>>(Pbuf, Hbuf, Hinit);
  s5b_scan<<<2 * NC * 6, 256, 0, stream>>>(delta, xs, Bst, Cst, Hinit, A_logs, Ds, yT);
  s6_out<<<2 * 216, 128, 0, stream>>>(yT, z, ln_w, ln_b, out_proj_w, out);
}